// Round 1
// baseline (90.853 us; speedup 1.0000x reference)
//
#include <hip/hip_runtime.h>

// out[b,n,i] = cb[n] + sum_{ff ≡ (i>>6) mod 4} x0[b, i&63, ff] * G[b,n,ff]
//   G[b,n,ff] = sum_y xk[b,y,ff] * w[n, ff>>2, y]
// bs=32, ts0=tsk=64, f=256, nf=128.
// Grid: 256 blocks = b(32) x nchunk(4, 32 n each) x ilhalf(2, 32 i_lo each).
// 256 threads. LDS 64KB: x0T[256][32] + Gs[256][32], XOR-swizzled 16B units.

__global__ __launch_bounds__(256)
void cin_fused(const float* __restrict__ x0,
               const float* __restrict__ xk,
               const float* __restrict__ w,
               const float* __restrict__ cb,
               float* __restrict__ out) {
    __shared__ float x0T[256 * 32]; // [ff][il_local]; unit u stored at u^(ff&7)
    __shared__ float Gs [256 * 32]; // [ff][n_local];  unit u stored at u^((ff>>2)&7)

    const int tid = threadIdx.x;
    const int bid = blockIdx.x;
    const int b   = bid >> 3;
    const int nb  = ((bid >> 1) & 3) * 32;   // n base for this block
    const int ih  = bid & 1;                 // i_lo half: i_lo = 32*ih + lil

    const float* x0b = x0 + (size_t)b * 64 * 256;
    const float* xkb = xk + (size_t)b * 64 * 256;

    // ---------------- Phase A: stage x0T[ff][lil] = x0[b, 32*ih + lil, ff]
    {
        const int ffc = tid;  // 0..255 — lanes read consecutive columns (coalesced)
        #pragma unroll
        for (int j = 0; j < 8; ++j) {       // lil unit = j (4 rows each)
            float4 v;
            v.x = x0b[(size_t)(32*ih + 4*j + 0) * 256 + ffc];
            v.y = x0b[(size_t)(32*ih + 4*j + 1) * 256 + ffc];
            v.z = x0b[(size_t)(32*ih + 4*j + 2) * 256 + ffc];
            v.w = x0b[(size_t)(32*ih + 4*j + 3) * 256 + ffc];
            const int phys = j ^ (ffc & 7);
            *reinterpret_cast<float4*>(&x0T[ffc * 32 + 4 * phys]) = v;
        }
    }

    // ---------------- Phase B: Gs[ff][nl] = sum_y w[nb+nl, ff>>2, y] * xk[b,y,ff]
    {
        const int t  = tid & 63;   // = lane: xk float4 loads coalesced across wave
        const int wv = tid >> 6;   // wave id -> owns n_local 8*wv..8*wv+7

        float gb[8][4];            // [kk = n offset][jj = ff offset]; ff = 4t+jj
        #pragma unroll
        for (int kk = 0; kk < 8; ++kk)
            #pragma unroll
            for (int jj = 0; jj < 4; ++jj) gb[kk][jj] = 0.f;

        for (int yt = 0; yt < 8; ++yt) {     // y tile of 8, xk cached in regs
            float xr[8][4];
            #pragma unroll
            for (int yy = 0; yy < 8; ++yy) {
                const float4 v = *reinterpret_cast<const float4*>(
                    &xkb[(size_t)(8*yt + yy) * 256 + 4*t]);
                xr[yy][0] = v.x; xr[yy][1] = v.y; xr[yy][2] = v.z; xr[yy][3] = v.w;
            }
            #pragma unroll
            for (int kk = 0; kk < 8; ++kk) {
                const float* wrow = w + (size_t)(nb + 8*wv + kk) * 4096 + t * 64 + 8*yt;
                #pragma unroll
                for (int y4 = 0; y4 < 2; ++y4) {   // two float4 of y per tile
                    const float4 wq = *reinterpret_cast<const float4*>(&wrow[4*y4]);
                    #pragma unroll
                    for (int jj = 0; jj < 4; ++jj) {
                        gb[kk][jj] += wq.x * xr[4*y4+0][jj];
                        gb[kk][jj] += wq.y * xr[4*y4+1][jj];
                        gb[kk][jj] += wq.z * xr[4*y4+2][jj];
                        gb[kk][jj] += wq.w * xr[4*y4+3][jj];
                    }
                }
            }
        }
        // write Gs: row 4t+jj, logical col-unit cu = 2*wv + u2 (cols 8wv+4u2+0..3)
        #pragma unroll
        for (int jj = 0; jj < 4; ++jj) {
            #pragma unroll
            for (int u2 = 0; u2 < 2; ++u2) {
                float4 v;
                v.x = gb[4*u2+0][jj];
                v.y = gb[4*u2+1][jj];
                v.z = gb[4*u2+2][jj];
                v.w = gb[4*u2+3][jj];
                const int cu   = 2*wv + u2;
                const int phys = cu ^ (t & 7);   // row>>2 == t
                *reinterpret_cast<float4*>(&Gs[(4*t + jj) * 32 + 4 * phys]) = v;
            }
        }
    }

    __syncthreads();

    // ---------------- Phase C: out[b, nb+4ng+j, ihi*64 + 32*ih + 4*iu + k]
    {
        const int ig  = tid & 31;
        const int ng  = tid >> 5;     // 0..7 -> n = nb + 4*ng + j
        const int ihi = ig >> 3;      // 0..3
        const int iu  = ig & 7;       // lil unit -> lil = 4*iu + k

        float acc[4][4];              // [k = i offset][j = n offset]
        #pragma unroll
        for (int k = 0; k < 4; ++k)
            #pragma unroll
            for (int j = 0; j < 4; ++j) acc[k][j] = 0.f;

        #pragma unroll 8
        for (int t = 0; t < 64; ++t) {
            const int ff = 4*t + ihi;
            const float4 xv = *reinterpret_cast<const float4*>(
                &x0T[ff * 32 + 4 * (iu ^ (ff & 7))]);
            const float4 gv = *reinterpret_cast<const float4*>(
                &Gs[ff * 32 + 4 * (ng ^ (t & 7))]);
            acc[0][0] += xv.x * gv.x; acc[0][1] += xv.x * gv.y;
            acc[0][2] += xv.x * gv.z; acc[0][3] += xv.x * gv.w;
            acc[1][0] += xv.y * gv.x; acc[1][1] += xv.y * gv.y;
            acc[1][2] += xv.y * gv.z; acc[1][3] += xv.y * gv.w;
            acc[2][0] += xv.z * gv.x; acc[2][1] += xv.z * gv.y;
            acc[2][2] += xv.z * gv.z; acc[2][3] += xv.z * gv.w;
            acc[3][0] += xv.w * gv.x; acc[3][1] += xv.w * gv.y;
            acc[3][2] += xv.w * gv.z; acc[3][3] += xv.w * gv.w;
        }

        float bias[4];
        #pragma unroll
        for (int j = 0; j < 4; ++j) bias[j] = cb[nb + 4*ng + j];

        #pragma unroll
        for (int j = 0; j < 4; ++j) {
            float4 v;
            v.x = acc[0][j] + bias[j];
            v.y = acc[1][j] + bias[j];
            v.z = acc[2][j] + bias[j];
            v.w = acc[3][j] + bias[j];
            float* dst = out + (size_t)(b * 128 + nb + 4*ng + j) * 256
                             + (ihi * 64 + 32*ih + 4*iu);
            *reinterpret_cast<float4*>(dst) = v;
        }
    }
}

extern "C" void kernel_launch(void* const* d_in, const int* in_sizes, int n_in,
                              void* d_out, int out_size, void* d_ws, size_t ws_size,
                              hipStream_t stream) {
    (void)in_sizes; (void)n_in; (void)out_size; (void)d_ws; (void)ws_size;
    const float* x0 = (const float*)d_in[0];
    const float* xk = (const float*)d_in[1];
    const float* w  = (const float*)d_in[2];
    const float* cb = (const float*)d_in[3];
    float* o = (float*)d_out;
    cin_fused<<<dim3(256), dim3(256), 0, stream>>>(x0, xk, w, cb, o);
}

// Round 3
// 77.120 us; speedup vs baseline: 1.1781x; 1.1781x over previous
//
#include <hip/hip_runtime.h>

// Factorized:  out[b,n,i] = cb[n] + sum_t x0[b, i&63, 4t+(i>>6)] * G[b,n,4t+(i>>6)]
//              G[b,n,4t+jj] = sum_y w[n,t,y] * xk[b,y,4t+jj]
// bs=32, ts0=tsk=64, f=256, nf=128.
//
// K_G:  per t: O_t[n=128][col=128] = W_t[128n x 64y] * X_t[64y x 128col], col = b*4+jj.
//       G stored in d_ws as G[col][t][n] (float), 4 MB.
// K_out: per (b,ihi): out[64il][128n] = sum_t x0[b,il,4t+ihi] * G[b*4+ihi][t][n] + cb[n].
// Both: 256 blocks x 256 threads, LDS tiles with XOR-swizzled 16B units, 4x4 reg tiles.

__global__ __launch_bounds__(256)
void kg_kernel(const float* __restrict__ w, const float* __restrict__ xk,
               float* __restrict__ G) {
    __shared__ float Wl[64 * 64];  // [y][n-unit swizzled]  (unit = 4 floats)
    __shared__ float Xl[64 * 64];  // [y][col-unit swizzled]

    const int tid = threadIdx.x;
    const int bid = blockIdx.x;
    const int t  = bid >> 2;        // 0..63
    const int nh = (bid >> 1) & 1;  // n half (64 each)
    const int ch = bid & 1;         // col half (64 each)

    // ---- stage W_t half: Wl[y][n] = w[nh*64+nl][t][y], transposed, swizzled
    #pragma unroll
    for (int r = 0; r < 4; ++r) {
        const int u  = tid + 256 * r;       // 0..1023
        const int nl = u >> 4;              // 0..63
        const int yq = u & 15;              // y quad
        const float4 v = *reinterpret_cast<const float4*>(
            w + (size_t)(nh * 64 + nl) * 4096 + t * 64 + 4 * yq);
        const int nu = nl >> 2, nd = nl & 3;
        const int y0 = 4 * yq;
        Wl[(y0 + 0) * 64 + ((nu ^ ((y0 + 0) & 15)) << 2) + nd] = v.x;
        Wl[(y0 + 1) * 64 + ((nu ^ ((y0 + 1) & 15)) << 2) + nd] = v.y;
        Wl[(y0 + 2) * 64 + ((nu ^ ((y0 + 2) & 15)) << 2) + nd] = v.z;
        Wl[(y0 + 3) * 64 + ((nu ^ ((y0 + 3) & 15)) << 2) + nd] = v.w;
    }
    // ---- stage X_t half: Xl[y][col] = xk[ch*16+bb][y][4t+jj], col-unit = bb
    #pragma unroll
    for (int r = 0; r < 4; ++r) {
        const int u  = tid + 256 * r;       // 0..1023
        const int bb = u >> 6;              // 0..15
        const int y  = u & 63;
        const float4 v = *reinterpret_cast<const float4*>(
            xk + (size_t)(ch * 16 + bb) * 16384 + y * 256 + 4 * t);
        *reinterpret_cast<float4*>(&Xl[y * 64 + ((bb ^ (y & 15)) << 2)]) = v;
    }
    __syncthreads();

    // ---- compute 4x4 per thread
    const int cq = tid & 15;   // col quad
    const int nq = tid >> 4;   // n quad
    float acc[4][4] = {};      // [k = n off][c = col off]
    #pragma unroll 8
    for (int y = 0; y < 64; ++y) {
        const int s = y & 15;
        const float4 wu = *reinterpret_cast<const float4*>(&Wl[y * 64 + ((nq ^ s) << 2)]);
        const float4 xu = *reinterpret_cast<const float4*>(&Xl[y * 64 + ((cq ^ s) << 2)]);
        acc[0][0] += wu.x * xu.x; acc[0][1] += wu.x * xu.y;
        acc[0][2] += wu.x * xu.z; acc[0][3] += wu.x * xu.w;
        acc[1][0] += wu.y * xu.x; acc[1][1] += wu.y * xu.y;
        acc[1][2] += wu.y * xu.z; acc[1][3] += wu.y * xu.w;
        acc[2][0] += wu.z * xu.x; acc[2][1] += wu.z * xu.y;
        acc[2][2] += wu.z * xu.z; acc[2][3] += wu.z * xu.w;
        acc[3][0] += wu.w * xu.x; acc[3][1] += wu.w * xu.y;
        acc[3][2] += wu.w * xu.z; acc[3][3] += wu.w * xu.w;
    }
    // ---- store G[col][t][n], f4 over n
    #pragma unroll
    for (int c = 0; c < 4; ++c) {
        const int col = ch * 64 + cq * 4 + c;
        const float4 v = make_float4(acc[0][c], acc[1][c], acc[2][c], acc[3][c]);
        *reinterpret_cast<float4*>(G + (size_t)(col * 64 + t) * 128 + nh * 64 + nq * 4) = v;
    }
}

__global__ __launch_bounds__(256)
void kout_kernel(const float* __restrict__ G, const float* __restrict__ x0,
                 const float* __restrict__ cb, float* __restrict__ out) {
    __shared__ float Gl[64 * 64];  // [t][n-unit swizzled]
    __shared__ float Xl[64 * 64];  // [t][il-unit swizzled]

    const int tid = threadIdx.x;
    const int bid = blockIdx.x;
    const int b   = bid >> 3;        // 0..31
    const int ihi = (bid >> 1) & 3;  // 0..3
    const int nh  = bid & 1;         // n half

    // ---- stage G half: Gl[t][n] = G[b*4+ihi][t][nh*64+n]
    const size_t gbase = (size_t)(b * 4 + ihi) * 8192 + nh * 64;
    #pragma unroll
    for (int r = 0; r < 4; ++r) {
        const int u = tid + 256 * r;   // 0..1023
        const int t = u >> 4;          // 0..63
        const int q = u & 15;          // n quad
        const float4 v = *reinterpret_cast<const float4*>(G + gbase + (size_t)t * 128 + 4 * q);
        *reinterpret_cast<float4*>(&Gl[t * 64 + ((q ^ (t & 15)) << 2)]) = v;
    }
    // ---- stage x0 quarter: Xl[t][il] = x0[b][il][4t+ihi]  (stride-4 gather)
    #pragma unroll
    for (int r = 0; r < 16; ++r) {
        const int u  = tid + 256 * r;  // 0..4095
        const int t  = u & 63;
        const int il = u >> 6;         // 0..63
        const float v = x0[(size_t)b * 16384 + il * 256 + 4 * t + ihi];
        Xl[t * 64 + (((il >> 2) ^ (t & 15)) << 2) + (il & 3)] = v;
    }
    __syncthreads();

    // ---- compute 4x4 per thread
    const int iu = tid & 15;  // il quad
    const int nu = tid >> 4;  // n quad
    float acc[4][4] = {};     // [a = il off][g = n off]
    #pragma unroll 8
    for (int t = 0; t < 64; ++t) {
        const int s = t & 15;
        const float4 xv = *reinterpret_cast<const float4*>(&Xl[t * 64 + ((iu ^ s) << 2)]);
        const float4 gv = *reinterpret_cast<const float4*>(&Gl[t * 64 + ((nu ^ s) << 2)]);
        acc[0][0] += xv.x * gv.x; acc[0][1] += xv.x * gv.y;
        acc[0][2] += xv.x * gv.z; acc[0][3] += xv.x * gv.w;
        acc[1][0] += xv.y * gv.x; acc[1][1] += xv.y * gv.y;
        acc[1][2] += xv.y * gv.z; acc[1][3] += xv.y * gv.w;
        acc[2][0] += xv.z * gv.x; acc[2][1] += xv.z * gv.y;
        acc[2][2] += xv.z * gv.z; acc[2][3] += xv.z * gv.w;
        acc[3][0] += xv.w * gv.x; acc[3][1] += xv.w * gv.y;
        acc[3][2] += xv.w * gv.z; acc[3][3] += xv.w * gv.w;
    }
    // ---- store out[b][n][ihi*64 + il] + bias, f4 over il
    const float4 cbv = *reinterpret_cast<const float4*>(cb + nh * 64 + nu * 4);
    #pragma unroll
    for (int g = 0; g < 4; ++g) {
        const int n = nh * 64 + nu * 4 + g;
        const float bias = (g == 0) ? cbv.x : (g == 1) ? cbv.y : (g == 2) ? cbv.z : cbv.w;
        const float4 v = make_float4(acc[0][g] + bias, acc[1][g] + bias,
                                     acc[2][g] + bias, acc[3][g] + bias);
        *reinterpret_cast<float4*>(out + (size_t)(b * 128 + n) * 256 + ihi * 64 + iu * 4) = v;
    }
}

extern "C" void kernel_launch(void* const* d_in, const int* in_sizes, int n_in,
                              void* d_out, int out_size, void* d_ws, size_t ws_size,
                              hipStream_t stream) {
    (void)in_sizes; (void)n_in; (void)out_size; (void)ws_size;
    const float* x0 = (const float*)d_in[0];
    const float* xk = (const float*)d_in[1];
    const float* w  = (const float*)d_in[2];
    const float* cb = (const float*)d_in[3];
    float* out = (float*)d_out;
    float* G   = (float*)d_ws;   // 4 MB: G[col=b*4+jj][t][n]

    kg_kernel<<<dim3(256), dim3(256), 0, stream>>>(w, xk, G);
    kout_kernel<<<dim3(256), dim3(256), 0, stream>>>(G, x0, cb, out);
}

// Round 7
// 71.380 us; speedup vs baseline: 1.2728x; 1.0804x over previous
//
#include <hip/hip_runtime.h>

// Factorized:  out[b,n,i] = cb[n] + sum_t x0[b, i&63, 4t+(i>>6)] * G[b,n,4t+(i>>6)]
//              G[b,n,4t+jj] = sum_y w[n,t,y] * xk[b,y,4t+jj]
// bs=32, ts0=tsk=64, f=256, nf=128.
// Split-bf16 MFMA (x = hi + lo; A*B = Ah*Bh + Ah*Bl + Al*Bh), fp32 acc:
//   error ~2^-16 rel, well under the 0.0156 tolerance; 16x16x32 MFMA.
// kg:  block (t, nh, ch): D[c][n] = sum_y X[c][y]*W[n][y] -> G[c][t][n] (fp32, d_ws)
// kout: block (b, ihi, nh): D[n][il] = sum_t G'[n][t]*X0[il][t] + cb -> out
// LDS: 4 tiles [64 rows][64 k] bf16 (8KB each), octet-XOR swizzled:
//   ushort idx = row*64 + ((k/8 ^ (row&7))*8) + k%8  -> frag read = 1 ds_read_b128.

typedef __attribute__((ext_vector_type(8))) short short8;
typedef __attribute__((ext_vector_type(4))) float f32x4;

__device__ __forceinline__ void split_bf16(float x, unsigned short& h, unsigned short& l) {
    const unsigned int xb = __float_as_uint(x);
    const unsigned int hb = xb & 0xFFFF0000u;          // truncated hi (exact split)
    h = (unsigned short)(hb >> 16);
    const float lo = x - __uint_as_float(hb);          // exact in fp32
    const unsigned int lb = __float_as_uint(lo);
    l = (unsigned short)((lb + 0x7FFFu + ((lb >> 16) & 1u)) >> 16);  // RNE
}

__device__ __forceinline__ short8 frag_at(const unsigned short* arr, int row, int oct) {
    return *reinterpret_cast<const short8*>(&arr[(row << 6) + (((oct ^ (row & 7)) << 3))]);
}

__global__ __launch_bounds__(256)
void kg_kernel(const float* __restrict__ w, const float* __restrict__ xk,
               float* __restrict__ G) {
    __shared__ unsigned short Ah[4096], Al[4096], Bh[4096], Bl[4096];
    const int tid = threadIdx.x;
    const int bid = blockIdx.x;
    const int t  = bid >> 2;        // 0..63
    const int nh = (bid >> 1) & 1;  // n half
    const int ch = bid & 1;         // col half

    // ---- B = W: Bh/Bl[n][y] = split(w[nh*64+n][t][y]); f4 global, b64 LDS writes
    #pragma unroll
    for (int r = 0; r < 4; ++r) {
        const int v  = tid + 256 * r;
        const int n  = v >> 4;          // 0..63
        const int yq = v & 15;          // y quad
        const float4 f = *reinterpret_cast<const float4*>(
            w + (size_t)(nh * 64 + n) * 4096 + t * 64 + 4 * yq);
        ushort4 ph, pl;
        split_bf16(f.x, ph.x, pl.x); split_bf16(f.y, ph.y, pl.y);
        split_bf16(f.z, ph.z, pl.z); split_bf16(f.w, ph.w, pl.w);
        const int idx = (n << 6) + (((yq >> 1) ^ (n & 7)) << 3) + ((yq & 1) << 2);
        *reinterpret_cast<ushort4*>(&Bh[idx]) = ph;
        *reinterpret_cast<ushort4*>(&Bl[idx]) = pl;
    }
    // ---- A = X: Ah/Al[c][y] = split(xk[ch*16+bq][y][4t+jj]), c = bq*4+jj (transpose)
    #pragma unroll
    for (int r = 0; r < 4; ++r) {
        const int v  = tid + 256 * r;
        const int bq = v >> 6;          // 0..15
        const int y  = v & 63;
        const float4 f = *reinterpret_cast<const float4*>(
            xk + (size_t)(ch * 16 + bq) * 16384 + y * 256 + 4 * t);
        const int o = y >> 3, yi = y & 7;
        const float vals[4] = {f.x, f.y, f.z, f.w};
        #pragma unroll
        for (int jj = 0; jj < 4; ++jj) {
            const int c = bq * 4 + jj;
            unsigned short h, l;
            split_bf16(vals[jj], h, l);
            const int idx = (c << 6) + ((o ^ (c & 7)) << 3) + yi;
            Ah[idx] = h; Al[idx] = l;
        }
    }
    __syncthreads();

    const int wv = tid >> 6, ln = tid & 63;
    const int lr = ln & 15, lg = ln >> 4;
    const int c0 = wv * 16;

    f32x4 acc[4] = {{0.f,0.f,0.f,0.f},{0.f,0.f,0.f,0.f},{0.f,0.f,0.f,0.f},{0.f,0.f,0.f,0.f}};
    #pragma unroll
    for (int s = 0; s < 2; ++s) {          // K = 64 -> two K=32 steps
        const int oct  = 4 * s + lg;
        const int arow = c0 + lr;
        const short8 a_h = frag_at(Ah, arow, oct);
        const short8 a_l = frag_at(Al, arow, oct);
        #pragma unroll
        for (int nt = 0; nt < 4; ++nt) {
            const int brow = nt * 16 + lr;
            const short8 b_h = frag_at(Bh, brow, oct);
            const short8 b_l = frag_at(Bl, brow, oct);
            acc[nt] = __builtin_amdgcn_mfma_f32_16x16x32_bf16(a_h, b_h, acc[nt], 0, 0, 0);
            acc[nt] = __builtin_amdgcn_mfma_f32_16x16x32_bf16(a_h, b_l, acc[nt], 0, 0, 0);
            acc[nt] = __builtin_amdgcn_mfma_f32_16x16x32_bf16(a_l, b_h, acc[nt], 0, 0, 0);
        }
    }
    // ---- store G[c][t][n]: D row = c (local), col = n (local); 16-lane groups coalesced
    #pragma unroll
    for (int nt = 0; nt < 4; ++nt)
        #pragma unroll
        for (int r = 0; r < 4; ++r) {
            const int c = ch * 64 + c0 + lg * 4 + r;
            G[(size_t)c * 8192 + t * 128 + nh * 64 + nt * 16 + lr] = acc[nt][r];
        }
}

__global__ __launch_bounds__(256)
void kout_kernel(const float* __restrict__ G, const float* __restrict__ x0,
                 const float* __restrict__ cb, float* __restrict__ out) {
    __shared__ unsigned short Ah[4096], Al[4096], Bh[4096], Bl[4096];
    const int tid = threadIdx.x;
    const int bid = blockIdx.x;
    const int b   = bid >> 3;        // 0..31
    const int ihi = (bid >> 1) & 3;  // 0..3
    const int nh  = bid & 1;         // n half
    const int c   = b * 4 + ihi;

    // ---- A = G': Ah/Al[n][t] = split(G[c][t][nh*64+n])  (transpose during split)
    #pragma unroll
    for (int r = 0; r < 4; ++r) {
        const int v  = tid + 256 * r;
        const int tt = v >> 4;          // 0..63
        const int nq = v & 15;          // n quad
        const float4 f = *reinterpret_cast<const float4*>(
            G + (size_t)c * 8192 + tt * 128 + nh * 64 + 4 * nq);
        const int o = tt >> 3, ti = tt & 7;
        const float vals[4] = {f.x, f.y, f.z, f.w};
        #pragma unroll
        for (int q = 0; q < 4; ++q) {
            const int n = 4 * nq + q;
            unsigned short h, l;
            split_bf16(vals[q], h, l);
            const int idx = (n << 6) + ((o ^ (n & 7)) << 3) + ti;
            Ah[idx] = h; Al[idx] = l;
        }
    }
    // ---- B = X0: Bh/Bl[il][t] = split(x0[b][il][4t+ihi])  (stride-4 gather)
    #pragma unroll
    for (int r = 0; r < 16; ++r) {
        const int v  = tid + 256 * r;
        const int il = v >> 6;          // 0..63
        const int tt = v & 63;
        const float x = x0[(size_t)b * 16384 + il * 256 + 4 * tt + ihi];
        unsigned short h, l;
        split_bf16(x, h, l);
        const int idx = (il << 6) + (((tt >> 3) ^ (il & 7)) << 3) + (tt & 7);
        Bh[idx] = h; Bl[idx] = l;
    }
    __syncthreads();

    const int wv = tid >> 6, ln = tid & 63;
    const int lr = ln & 15, lg = ln >> 4;
    const int n0 = wv * 16;

    f32x4 acc[4] = {{0.f,0.f,0.f,0.f},{0.f,0.f,0.f,0.f},{0.f,0.f,0.f,0.f},{0.f,0.f,0.f,0.f}};
    #pragma unroll
    for (int s = 0; s < 2; ++s) {
        const int oct  = 4 * s + lg;
        const int arow = n0 + lr;
        const short8 a_h = frag_at(Ah, arow, oct);
        const short8 a_l = frag_at(Al, arow, oct);
        #pragma unroll
        for (int it = 0; it < 4; ++it) {
            const int brow = it * 16 + lr;
            const short8 b_h = frag_at(Bh, brow, oct);
            const short8 b_l = frag_at(Bl, brow, oct);
            acc[it] = __builtin_amdgcn_mfma_f32_16x16x32_bf16(a_h, b_h, acc[it], 0, 0, 0);
            acc[it] = __builtin_amdgcn_mfma_f32_16x16x32_bf16(a_h, b_l, acc[it], 0, 0, 0);
            acc[it] = __builtin_amdgcn_mfma_f32_16x16x32_bf16(a_l, b_h, acc[it], 0, 0, 0);
        }
    }
    // ---- bias + store: D row = n (local), col = il; 16-lane groups coalesced
    float bias[4];
    #pragma unroll
    for (int r = 0; r < 4; ++r) bias[r] = cb[nh * 64 + n0 + lg * 4 + r];
    #pragma unroll
    for (int it = 0; it < 4; ++it)
        #pragma unroll
        for (int r = 0; r < 4; ++r) {
            const int n = nh * 64 + n0 + lg * 4 + r;
            out[(size_t)b * 32768 + (size_t)n * 256 + ihi * 64 + it * 16 + lr]
                = acc[it][r] + bias[r];
        }
}

extern "C" void kernel_launch(void* const* d_in, const int* in_sizes, int n_in,
                              void* d_out, int out_size, void* d_ws, size_t ws_size,
                              hipStream_t stream) {
    (void)in_sizes; (void)n_in; (void)out_size; (void)ws_size;
    const float* x0 = (const float*)d_in[0];
    const float* xk = (const float*)d_in[1];
    const float* w  = (const float*)d_in[2];
    const float* cb = (const float*)d_in[3];
    float* out = (float*)d_out;
    float* G   = (float*)d_ws;   // 4 MB: G[col=b*4+jj][t][n], fp32

    kg_kernel<<<dim3(256), dim3(256), 0, stream>>>(w, xk, G);
    kout_kernel<<<dim3(256), dim3(256), 0, stream>>>(G, x0, cb, out);
}